// Round 21
// baseline (227.092 us; speedup 1.0000x reference)
//
#include <hip/hip_runtime.h>
#include <math.h>

#define B_ 4
#define C_ 256
#define CH_ 128
#define NN 4096   // H*W = 64*64
#define LOG2E 1.4426950408889634f

typedef __bf16 bf16x8 __attribute__((ext_vector_type(8)));
typedef float f32x16 __attribute__((ext_vector_type(16)));
typedef unsigned int u32;

__device__ __forceinline__ float gelu_erf(float x) {
    return 0.5f * x * (1.0f + erff(x * 0.7071067811865476f));
}

__device__ __forceinline__ u32 pkbf(float a, float b) {
    union { __bf16 h[2]; u32 u; } x;
    x.h[0] = (__bf16)a; x.h[1] = (__bf16)b;
    return x.u;
}

// ---------------------------------------------------------------------------
// NCHW fp32 -> channel-chunked bf16 [b][ch/16][4096][16], both inputs.
// ---------------------------------------------------------------------------
__global__ __launch_bounds__(256) void nhwc_cast2_kernel(
    const float* __restrict__ in0, const float* __restrict__ in1,
    __bf16* __restrict__ Xt0c, __bf16* __restrict__ Xin1c)
{
    __shared__ float Lt[64][65];
    const int t = threadIdx.x;
    const int p0 = blockIdx.x * 64;
    const int c0 = blockIdx.y * 64;
    const int z = blockIdx.z;
    const int b = z & 3;
    const float* src; __bf16* dst; int chbase, nch;
    if (z < 4) { src = in0; dst = Xt0c;  chbase = 256; nch = 32; }
    else       { src = in1; dst = Xin1c; chbase = 0;   nch = 16; }
#pragma unroll
    for (int i = 0; i < 16; ++i) {
        int idx = t + i * 256;
        int c = idx >> 6, p = idx & 63;
        Lt[c][p] = src[((size_t)(b * 256 + c0 + c)) * 4096 + p0 + p];
    }
    __syncthreads();
#pragma unroll
    for (int i = 0; i < 16; ++i) {
        int idx = t + i * 256;
        int p = idx >> 6, c = idx & 63;
        const int ch = chbase + c0 + c;
        dst[(((size_t)(b * nch + (ch >> 4)) * 4096) + p0 + p) * 16 + (ch & 15)]
            = (__bf16)Lt[c][p];
    }
}

// ---------------------------------------------------------------------------
// Weight transform. wvb (feeds ONLY the Q projection) is pre-scaled by
// LOG2E so attention S-values arrive in log2 domain (exp -> exp2).
// ---------------------------------------------------------------------------
__global__ __launch_bounds__(256) void wtrans_kernel(
    const float* __restrict__ w0, const float* __restrict__ w1,
    const float* __restrict__ wq, const float* __restrict__ wk,
    const float* __restrict__ wv, const float* __restrict__ wo,
    __bf16* __restrict__ Wt0, __bf16* __restrict__ Wt1,
    __bf16* __restrict__ wqb, __bf16* __restrict__ wkb,
    __bf16* __restrict__ wvb, __bf16* __restrict__ wob)
{
    int id = blockIdx.x * 256 + threadIdx.x;
    if (id < 131072) {
        int o = id >> 9, ci = id & 511;
        const float* s = w0 + (size_t)id * 9;
        const int chunk = ci >> 4, f = o >> 5;
        const int lane = (o & 31) + 32 * ((ci >> 3) & 1);
        const int j = ci & 7;
#pragma unroll
        for (int k = 0; k < 9; ++k)
            Wt0[((size_t)(chunk * 9 + k) * 8 + f) * 512 + lane * 8 + j] = (__bf16)s[k];
    } else if (id < 196608) {
        int id2 = id - 131072;
        int o = id2 >> 8, ci = id2 & 255;
        const float* s = w1 + (size_t)id2 * 9;
        const int chunk = ci >> 4, f = o >> 5;
        const int lane = (o & 31) + 32 * ((ci >> 3) & 1);
        const int j = ci & 7;
#pragma unroll
        for (int k = 0; k < 9; ++k)
            Wt1[((size_t)(chunk * 9 + k) * 8 + f) * 512 + lane * 8 + j] = (__bf16)s[k];
    } else {
        int id3 = id - 196608;     // 0..131071
        int sel = id3 >> 15;
        int k = id3 & 32767;
        const float* s = sel == 0 ? wq : sel == 1 ? wk : sel == 2 ? wv : wo;
        __bf16* d = sel == 0 ? wqb : sel == 1 ? wkb : sel == 2 ? wvb : wob;
        const float scale = (sel == 2) ? LOG2E : 1.0f;
        d[k] = (__bf16)(s[k] * scale);
    }
}

// ---------------------------------------------------------------------------
// 1x1 projections via MFMA; inputs channel-chunked, outputs frag-major.
// Q projection (which==2) bias also pre-scaled by LOG2E.
// ---------------------------------------------------------------------------
__global__ __launch_bounds__(256) void proj_mfma_kernel(
    const __bf16* __restrict__ Xt0c,  // [4][32][4096][16], in0 at chunks 16-31
    const __bf16* __restrict__ Xin1c, // [4][16][4096][16]
    const __bf16* __restrict__ wqb, const __bf16* __restrict__ wkb,
    const __bf16* __restrict__ wvb,
    const float* __restrict__ bq, const float* __restrict__ bk,
    const float* __restrict__ bv,
    __bf16* __restrict__ Vswz, __bf16* __restrict__ Kswz, __bf16* __restrict__ Qswz)
{
    __shared__ __align__(16) __bf16 Vt[4][64][80];
    __shared__ float biasl[128];

    const int t = threadIdx.x;
    const int which = blockIdx.z % 3;
    const int b = blockIdx.z / 3;
    const int p0 = blockIdx.x * 128;

    const __bf16* W = which == 0 ? wqb : which == 1 ? wkb : wvb;
    const float* bias = which == 0 ? bq : which == 1 ? bk : bv;
    const __bf16* src = (which == 2)
        ? Xin1c + (size_t)b * 16 * 4096 * 16
        : Xt0c  + ((size_t)(b * 32 + 16)) * 4096 * 16;

    if (t < 128) biasl[t] = bias[t] * (which == 2 ? LOG2E : 1.0f);
    __syncthreads();

    const int lane = t & 63, w = t >> 6;
    const int l31 = lane & 31, hi = lane >> 5;
    const int wo2 = w >> 1, wp2 = w & 1;
    const int ob = wo2 * 64;
    const int pb = p0 + wp2 * 64;

    f32x16 acc[2][2];
#pragma unroll
    for (int i = 0; i < 2; ++i)
#pragma unroll
        for (int j = 0; j < 2; ++j)
#pragma unroll
            for (int e = 0; e < 16; ++e) acc[i][j][e] = 0.f;

#pragma unroll
    for (int kc = 0; kc < 16; ++kc) {
        bf16x8 a0 = *(const bf16x8*)&W[(size_t)(ob + l31) * 256 + hi * 8 + kc * 16];
        bf16x8 a1 = *(const bf16x8*)&W[(size_t)(ob + 32 + l31) * 256 + hi * 8 + kc * 16];
        bf16x8 b0 = *(const bf16x8*)&src[((size_t)kc * 4096 + pb + l31) * 16 + hi * 8];
        bf16x8 b1 = *(const bf16x8*)&src[((size_t)kc * 4096 + pb + 32 + l31) * 16 + hi * 8];
        acc[0][0] = __builtin_amdgcn_mfma_f32_32x32x16_bf16(a0, b0, acc[0][0], 0, 0, 0);
        acc[0][1] = __builtin_amdgcn_mfma_f32_32x32x16_bf16(a0, b1, acc[0][1], 0, 0, 0);
        acc[1][0] = __builtin_amdgcn_mfma_f32_32x32x16_bf16(a1, b0, acc[1][0], 0, 0, 0);
        acc[1][1] = __builtin_amdgcn_mfma_f32_32x32x16_bf16(a1, b1, acc[1][1], 0, 0, 0);
    }

    if (which) {
        __bf16* dst = (which == 1 ? Kswz : Qswz) + (size_t)b * NN * CH_;
#pragma unroll
        for (int mi = 0; mi < 2; ++mi)
#pragma unroll
            for (int nx = 0; nx < 2; ++nx) {
                const int tile = (pb >> 5) + nx;
#pragma unroll
                for (int q4 = 0; q4 < 4; ++q4) {
                    const int ic = (ob >> 4) + mi * 2 + (q4 >> 1);
                    const int og = ob + mi * 32 + q4 * 8 + hi * 4;
                    __bf16 pk[4];
#pragma unroll
                    for (int j = 0; j < 4; ++j)
                        pk[j] = (__bf16)(acc[mi][nx][q4 * 4 + j] + biasl[og + j]);
                    const size_t el = ((size_t)(tile * 8 + ic) * 64
                                       + l31 + 32 * (q4 & 1)) * 8 + hi * 4;
                    *(uint2*)&dst[el] = *(const uint2*)pk;
                }
            }
    } else {
#pragma unroll
        for (int mi = 0; mi < 2; ++mi)
#pragma unroll
            for (int nx = 0; nx < 2; ++nx) {
                const int ploc = nx * 32 + l31;
#pragma unroll
                for (int q4 = 0; q4 < 4; ++q4) {
                    const int oloc = mi * 32 + q4 * 8 + hi * 4;
#pragma unroll
                    for (int j = 0; j < 4; ++j)
                        Vt[w][oloc + j][ploc] =
                            (__bf16)(acc[mi][nx][q4 * 4 + j] + biasl[ob + oloc + j]);
                }
            }
        __syncthreads();
        __bf16* dst = Vswz + (size_t)b * NN * CH_;
#pragma unroll
        for (int s = 0; s < 8; ++s) {
            const int tl = s >> 2, jc = (s >> 1) & 1, il = s & 1;
            const int tile_g = (pb >> 5) + tl;
            const int icf_g = (ob >> 5) + il;
            const int i_loc = il * 32 + l31;
            const int kk = tl * 32 + jc * 16 + hi * 8;
            uint4 v = *(const uint4*)&Vt[w][i_loc][kk];
            const size_t el = ((size_t)((tile_g * 2 + jc) * 4 + icf_g) * 64 + lane) * 8;
            *(uint4*)&dst[el] = v;
        }
    }
}

// ---------------------------------------------------------------------------
// MFMA bf16 flash attention — R20 structure with log2-domain softmax:
// Q pre-scaled by LOG2E, so every exp is a bare v_exp_f32 (exp2f), saving
// ~17 v_mul per tile on the critical softmax chain. Numerics identical.
// grid 1024, block 256.
// ---------------------------------------------------------------------------
__global__ __launch_bounds__(256, 4) void attn_mfma_kernel(
    const __bf16* __restrict__ Qswz, const __bf16* __restrict__ Kswz,
    const __bf16* __restrict__ Vswz,
    __bf16* __restrict__ Opart, float* __restrict__ Mpart, float* __restrict__ Lpart)
{
    __shared__ __bf16 Op[4][128][34];
    __shared__ float Ml[4][32], Ll[4][32];

    const int t = threadIdx.x;
    const int lane = t & 63;
    const int w = t >> 6;
    const int l31 = lane & 31;
    const int hi = lane >> 5;

    const int bid = blockIdx.x;
    const int xcd = bid & 7;
    const int b = xcd >> 1;
    const int local = bid >> 3;
    const int qt = (xcd & 1) * 64 + (local & 63);
    const int half = local >> 6;
    const int q0 = qt * 32;

    const __bf16* Qs = Qswz + (size_t)b * NN * CH_ + (size_t)qt * 4096 + lane * 8;
    bf16x8 qf[8];
#pragma unroll
    for (int ic = 0; ic < 8; ++ic) qf[ic] = *(const bf16x8*)(Qs + ic * 512);

    const __bf16* Ks = Kswz + (size_t)b * NN * CH_ + lane * 8;
    const __bf16* Vs = Vswz + (size_t)b * NN * CH_ + lane * 8;

    f32x16 oacc[4];
#pragma unroll
    for (int i = 0; i < 4; ++i)
#pragma unroll
        for (int e = 0; e < 16; ++e) oacc[i][e] = 0.f;

    float m = -3e38f, lsum = 0.f;
    const int tbase = half * 64 + w * 16;

    for (int jt = 0; jt < 16; ++jt) {
        const int tile = tbase + jt;
        f32x16 s;
#pragma unroll
        for (int e = 0; e < 16; ++e) s[e] = 0.f;
        // split bases: all load immediates stay within +-4096B
        const __bf16* KtA = Ks + (size_t)tile * 4096;
        const __bf16* KtB = KtA + 2048;
#pragma unroll
        for (int ic = 0; ic < 4; ++ic) {
            bf16x8 kf0 = *(const bf16x8*)(KtA + ic * 512);
            bf16x8 kf1 = *(const bf16x8*)(KtB + ic * 512);
            s = __builtin_amdgcn_mfma_f32_32x32x16_bf16(kf0, qf[ic], s, 0, 0, 0);
            s = __builtin_amdgcn_mfma_f32_32x32x16_bf16(kf1, qf[ic + 4], s, 0, 0, 0);
        }
        // max tree via v_max3-fusable triples
        float t8[8];
#pragma unroll
        for (int e = 0; e < 8; ++e) t8[e] = fmaxf(s[e], s[e + 8]);
        const float ta = fmaxf(fmaxf(t8[0], t8[1]), t8[2]);
        const float tb = fmaxf(fmaxf(t8[3], t8[4]), t8[5]);
        const float tc = fmaxf(t8[6], t8[7]);
        float mu = fmaxf(fmaxf(ta, tb), tc);
        const float pm = fmaxf(mu, __shfl_xor(mu, 32));
        if (!__all(pm <= m + 8.f)) {
            const float mn = fmaxf(m, pm);
            const float al = exp2f(m - mn);
            m = mn;
            lsum *= al;
#pragma unroll
            for (int i = 0; i < 4; ++i)
#pragma unroll
                for (int e = 0; e < 16; ++e) oacc[i][e] *= al;
        }
#pragma unroll
        for (int e = 0; e < 16; ++e) s[e] = exp2f(s[e] - m);
        float s8[8];
#pragma unroll
        for (int e = 0; e < 8; ++e) s8[e] = s[e] + s[e + 8];
#pragma unroll
        for (int e = 0; e < 4; ++e) s8[e] += s8[e + 4];
        s8[0] += s8[2]; s8[1] += s8[3];
        float su = s8[0] + s8[1];
        lsum += su + __shfl_xor(su, 32);

        const __bf16* VtA = Vs + (size_t)tile * 4096;
        const __bf16* VtB = VtA + 2048;
        {
            u32 w0 = pkbf(s[0], s[1]), w1 = pkbf(s[2], s[3]);
            u32 w2 = pkbf(s[4], s[5]), w3 = pkbf(s[6], s[7]);
            asm("v_permlane32_swap_b32 %0, %1" : "+v"(w0), "+v"(w2));
            asm("v_permlane32_swap_b32 %0, %1" : "+v"(w1), "+v"(w3));
            union { u32 u4[4]; bf16x8 v; } pB;
            pB.u4[0] = w0; pB.u4[1] = w1; pB.u4[2] = w2; pB.u4[3] = w3;
#pragma unroll
            for (int icf = 0; icf < 4; ++icf) {
                bf16x8 vf = *(const bf16x8*)(VtA + icf * 512);
                oacc[icf] = __builtin_amdgcn_mfma_f32_32x32x16_bf16(vf, pB.v, oacc[icf], 0, 0, 0);
            }
        }
        {
            u32 w0 = pkbf(s[8], s[9]), w1 = pkbf(s[10], s[11]);
            u32 w2 = pkbf(s[12], s[13]), w3 = pkbf(s[14], s[15]);
            asm("v_permlane32_swap_b32 %0, %1" : "+v"(w0), "+v"(w2));
            asm("v_permlane32_swap_b32 %0, %1" : "+v"(w1), "+v"(w3));
            union { u32 u4[4]; bf16x8 v; } pB;
            pB.u4[0] = w0; pB.u4[1] = w1; pB.u4[2] = w2; pB.u4[3] = w3;
#pragma unroll
            for (int icf = 0; icf < 4; ++icf) {
                bf16x8 vf = *(const bf16x8*)(VtB + icf * 512);
                oacc[icf] = __builtin_amdgcn_mfma_f32_32x32x16_bf16(vf, pB.v, oacc[icf], 0, 0, 0);
            }
        }
    }

#pragma unroll
    for (int icf = 0; icf < 4; ++icf)
#pragma unroll
        for (int q = 0; q < 16; ++q) {
            const int row = icf * 32 + (q & 3) + 8 * (q >> 2) + 4 * hi;
            Op[w][row][l31] = (__bf16)oacc[icf][q];
        }
    if (hi == 0) { Ml[w][l31] = m; Ll[w][l31] = lsum; }
    __syncthreads();
    {
        const int q = t & 31;
        const int i0g = (t >> 5) * 16;
        const float m0 = Ml[0][q], m1 = Ml[1][q], m2 = Ml[2][q], m3 = Ml[3][q];
        const float ms = fmaxf(fmaxf(m0, m1), fmaxf(m2, m3));
        const float a0 = exp2f(m0 - ms), a1 = exp2f(m1 - ms);
        const float a2 = exp2f(m2 - ms), a3 = exp2f(m3 - ms);
        const float den = a0 * Ll[0][q] + a1 * Ll[1][q] + a2 * Ll[2][q] + a3 * Ll[3][q];
        union { __bf16 h[16]; uint4 u4[2]; } pk;
#pragma unroll
        for (int ii = 0; ii < 16; ++ii) {
            const int i = i0g + ii;
            pk.h[ii] = (__bf16)(a0 * (float)Op[0][i][q] + a1 * (float)Op[1][i][q]
                              + a2 * (float)Op[2][i][q] + a3 * (float)Op[3][i][q]);
        }
        const size_t base = ((size_t)((half * 4 + b) * NN) + q0 + q) * CH_ + i0g;
        *(uint4*)&Opart[base] = pk.u4[0];
        *(uint4*)&Opart[base + 8] = pk.u4[1];
        if (t < 32) {
            Mpart[(size_t)(half * 4 + b) * NN + q0 + q] = ms;
            Lpart[(size_t)(half * 4 + b) * NN + q0 + q] = den;
        }
    }
}

// ---------------------------------------------------------------------------
// Merge the 2 KV-half partials -> x0 bf16 pos-major [4][4096][128]
// (m values are in log2 domain -> exp2f)
// ---------------------------------------------------------------------------
__global__ __launch_bounds__(256) void attn_merge_kernel(
    const __bf16* __restrict__ Opart, const float* __restrict__ Mpart,
    const float* __restrict__ Lpart, __bf16* __restrict__ x0)
{
    const int id = blockIdx.x * 256 + threadIdx.x;
    const int qg = id >> 2;
    const int i0 = (id & 3) * 32;
    const int b = qg >> 12, q = qg & 4095;
    const size_t idx0 = (size_t)b * NN + q;
    const size_t idx1 = (size_t)(4 + b) * NN + q;
    const float m0 = Mpart[idx0], m1 = Mpart[idx1];
    const float ms = fmaxf(m0, m1);
    const float a0 = exp2f(m0 - ms), a1 = exp2f(m1 - ms);
    const float inv = 1.f / (a0 * Lpart[idx0] + a1 * Lpart[idx1]);
    const __bf16* O0 = &Opart[idx0 * CH_ + i0];
    const __bf16* O1 = &Opart[idx1 * CH_ + i0];
    union { __bf16 h[32]; uint4 u4[4]; } ov;
#pragma unroll
    for (int ii = 0; ii < 32; ++ii)
        ov.h[ii] = (__bf16)((a0 * (float)O0[ii] + a1 * (float)O1[ii]) * inv);
    uint4* dst = (uint4*)&x0[((size_t)b * NN + q) * CH_ + i0];
#pragma unroll
    for (int s = 0; s < 4; ++s) dst[s] = ov.u4[s];
}

// ---------------------------------------------------------------------------
// conv_o (1x1, 128->256) via MFMA + BN + GELU -> Xt0c chunks 0-15
// ---------------------------------------------------------------------------
__global__ __launch_bounds__(256) void convo_mfma_kernel(
    const __bf16* __restrict__ x0, const __bf16* __restrict__ wob,
    const float* __restrict__ bo,
    const float* __restrict__ g, const float* __restrict__ bb,
    const float* __restrict__ mm, const float* __restrict__ vv,
    __bf16* __restrict__ Xt0c)
{
    __shared__ float scb[128], shb[128], bsb[128];
    const int t = threadIdx.x;
    const int p0 = blockIdx.x * 128;
    const int o0 = blockIdx.y * 128;
    const int b = blockIdx.z;
    if (t < 128) {
        const int o = o0 + t;
        const float sc = g[o] * rsqrtf(vv[o] + 1e-5f);
        scb[t] = sc; shb[t] = bb[o] - mm[o] * sc; bsb[t] = bo[o];
    }
    __syncthreads();

    const int lane = t & 63, w = t >> 6;
    const int l31 = lane & 31, hi = lane >> 5;
    const int wo2 = w >> 1, wp2 = w & 1;
    const int ob = o0 + wo2 * 64;
    const int pb = p0 + wp2 * 64;

    f32x16 acc[2][2];
#pragma unroll
    for (int i = 0; i < 2; ++i)
#pragma unroll
        for (int j = 0; j < 2; ++j)
#pragma unroll
            for (int e = 0; e < 16; ++e) acc[i][j][e] = 0.f;

#pragma unroll
    for (int kc = 0; kc < 8; ++kc) {
        bf16x8 a0 = *(const bf16x8*)&wob[(size_t)(ob + l31) * 128 + hi * 8 + kc * 16];
        bf16x8 a1 = *(const bf16x8*)&wob[(size_t)(ob + 32 + l31) * 128 + hi * 8 + kc * 16];
        bf16x8 b0 = *(const bf16x8*)&x0[((size_t)(b * NN) + pb + l31) * 128 + hi * 8 + kc * 16];
        bf16x8 b1 = *(const bf16x8*)&x0[((size_t)(b * NN) + pb + 32 + l31) * 128 + hi * 8 + kc * 16];
        acc[0][0] = __builtin_amdgcn_mfma_f32_32x32x16_bf16(a0, b0, acc[0][0], 0, 0, 0);
        acc[0][1] = __builtin_amdgcn_mfma_f32_32x32x16_bf16(a0, b1, acc[0][1], 0, 0, 0);
        acc[1][0] = __builtin_amdgcn_mfma_f32_32x32x16_bf16(a1, b0, acc[1][0], 0, 0, 0);
        acc[1][1] = __builtin_amdgcn_mfma_f32_32x32x16_bf16(a1, b1, acc[1][1], 0, 0, 0);
    }

#pragma unroll
    for (int mi = 0; mi < 2; ++mi)
#pragma unroll
        for (int nx = 0; nx < 2; ++nx) {
            const int p = pb + nx * 32 + l31;
#pragma unroll
            for (int q4 = 0; q4 < 4; ++q4) {
                const int ol = wo2 * 64 + mi * 32 + q4 * 8 + hi * 4;
                const int chg = o0 + ol;   // global out channel
                __bf16 pk[4];
#pragma unroll
                for (int j = 0; j < 4; ++j) {
                    float v = acc[mi][nx][q4 * 4 + j] + bsb[ol + j];
                    v = v * scb[ol + j] + shb[ol + j];
                    pk[j] = (__bf16)gelu_erf(v);
                }
                *(uint2*)&Xt0c[(((size_t)(b * 32 + (chg >> 4)) * 4096) + p) * 16 + (chg & 15)]
                    = *(const uint2*)pk;
            }
        }
}

// ---------------------------------------------------------------------------
// 3x3 conv via MFMA — channel-chunked input, raw barrier, reg weights,
// L2-aware XCD map. (R17-proven, unchanged.)
// ---------------------------------------------------------------------------
template<int IC, bool FUSEMAX>
__global__ __launch_bounds__(128) void conv3x3_mfma_kernel(
    const __bf16* __restrict__ Xsrc,   // chunked [4][IC/16][4096][16]
    const __bf16* __restrict__ Wf,     // frag-major [chunk16][9][8][64][8]
    const float* __restrict__ bias, const float* __restrict__ bng,
    const float* __restrict__ bnb, const float* __restrict__ bnm,
    const float* __restrict__ bnv,
    __bf16* __restrict__ out,          // chunked [4][16][4096][16] (FUSEMAX=0)
    const __bf16* __restrict__ Xg,     // Xt0c (x0g at chunks 0-15) (FUSEMAX=1)
    float* __restrict__ part)          // [4][64][256] partial max (FUSEMAX=1)
{
    constexpr int NC = IC / 16;
    __shared__ __align__(16) char Tl[2][6336];   // [3 rows][66 xh][16 ci] bf16
    __shared__ float scb[64], shb[64], bsb[64];
    __shared__ float red[2][64];

    const int t = threadIdx.x;
    const int bid = blockIdx.x;
    const int xcd = bid & 7, local = bid >> 3;        // local 0..127
    const int b = xcd >> 1, yhi = xcd & 1;
    const int y0 = yhi * 32 + (local & 31);           // output row
    const int m = local >> 5;
    const int o0 = m * 64;

    if (t < 64) {
        const int o = o0 + t;
        const float sc = bng[o] * rsqrtf(bnv[o] + 1e-5f);
        scb[t] = sc; shb[t] = bnb[o] - bnm[o] * sc; bsb[t] = bias[o];
    }

    const int lane = t & 63, w = t >> 6;   // w = x-half (0,1)
    const int l31 = lane & 31, hi = lane >> 5;

    uint4 ireg[3];

    auto loadI = [&](int cc) {             // cc = input channel-chunk index
        const __bf16* base = Xsrc + ((size_t)(b * NC + cc)) * 4096 * 16;
#pragma unroll
        for (int s = 0; s < 3; ++s) {
            int u = t + s * 128;
            int g = u & 1, x = (u >> 1) & 63, r = u >> 7;   // r 0..2
            int yy = y0 - 1 + r;
            if (yy >= 0 && yy < 64)
                ireg[s] = *(const uint4*)&base[((size_t)(yy * 64 + x)) * 16 + g * 8];
            else
                ireg[s] = make_uint4(0u, 0u, 0u, 0u);
        }
    };
    auto writeI = [&](char* dst) {
#pragma unroll
        for (int s = 0; s < 3; ++s) {
            int u = t + s * 128;
            int g = u & 1, x = (u >> 1) & 63, r = u >> 7;
            int xh = x + 1;
            int byte = r * 2112 + ((xh * 32 + g * 16) ^ ((xh & 7) << 4));
            *(uint4*)(dst + byte) = ireg[s];
        }
        if (t < 12) {
            int g = t & 1, side = (t >> 1) & 1, r = t >> 2;
            int xh = side ? 65 : 0;
            int byte = r * 2112 + ((xh * 32 + g * 16) ^ ((xh & 7) << 4));
            *(uint4*)(dst + byte) = make_uint4(0u, 0u, 0u, 0u);
        }
    };

    const __bf16* Wb = Wf + ((size_t)(m * 2) * 64 + lane) * 8;
    bf16x8 wA[9][2];
    auto loadA = [&](int c) {
#pragma unroll
        for (int k9 = 0; k9 < 9; ++k9) {
            const __bf16* wp = Wb + (size_t)(c * 9 + k9) * 4096;
            wA[k9][0] = *(const bf16x8*)(wp);
            wA[k9][1] = *(const bf16x8*)(wp + 512);
        }
    };

    f32x16 acc[2];
#pragma unroll
    for (int i = 0; i < 2; ++i)
#pragma unroll
        for (int e = 0; e < 16; ++e) acc[i][e] = 0.f;

    int Boff[3];
#pragma unroll
    for (int dx = 0; dx < 3; ++dx) {
        int xh = w * 32 + l31 + dx;
        Boff[dx] = (xh * 32 + hi * 16) ^ ((xh & 7) << 4);
    }

    auto compute = [&](const char* Tb) {
#pragma unroll
        for (int k9 = 0; k9 < 9; ++k9) {
            const int dy = k9 / 3, dx = k9 % 3;
            bf16x8 bv = *(const bf16x8*)(Tb + dy * 2112 + Boff[dx]);
            acc[0] = __builtin_amdgcn_mfma_f32_32x32x16_bf16(wA[k9][0], bv, acc[0], 0, 0, 0);
            acc[1] = __builtin_amdgcn_mfma_f32_32x32x16_bf16(wA[k9][1], bv, acc[1], 0, 0, 0);
        }
    };

    loadI(0); loadA(0);
    writeI(Tl[0]);
    asm volatile("s_waitcnt lgkmcnt(0)" ::: "memory");
    __builtin_amdgcn_s_barrier();
    for (int c = 0; c < NC; ++c) {
        const int cur = c & 1;
        if (c + 1 < NC) loadI(c + 1);
        compute(Tl[cur]);
        if (c + 1 < NC) { loadA(c + 1); writeI(Tl[cur ^ 1]); }
        asm volatile("s_waitcnt lgkmcnt(0)" ::: "memory");
        __builtin_amdgcn_s_barrier();
    }

    const int p = y0 * 64 + w * 32 + l31;
    if constexpr (!FUSEMAX) {
#pragma unroll
        for (int mi = 0; mi < 2; ++mi)
#pragma unroll
            for (int q = 0; q < 4; ++q) {
                const int obase = mi * 32 + q * 8 + hi * 4;
                const int chg = o0 + obase;
                __bf16 pk[4];
#pragma unroll
                for (int j = 0; j < 4; ++j) {
                    float v = acc[mi][q * 4 + j] + bsb[obase + j];
                    v = v * scb[obase + j] + shb[obase + j];
                    pk[j] = (__bf16)gelu_erf(v);
                }
                *(uint2*)&out[(((size_t)(b * 16 + (chg >> 4)) * 4096) + p) * 16 + (chg & 15)]
                    = *(const uint2*)pk;
            }
    } else {
#pragma unroll
        for (int mi = 0; mi < 2; ++mi)
#pragma unroll
            for (int q = 0; q < 4; ++q) {
                const int obase = mi * 32 + q * 8 + hi * 4;
                const int chg = o0 + obase;
                union { uint2 u; __bf16 h[4]; } xg;
                xg.u = *(const uint2*)&Xg[(((size_t)(b * 32 + (chg >> 4)) * 4096) + p) * 16
                                          + (chg & 15)];
#pragma unroll
                for (int j = 0; j < 4; ++j) {
                    float v = acc[mi][q * 4 + j] + bsb[obase + j];
                    v = v * scb[obase + j] + shb[obase + j];
                    acc[mi][q * 4 + j] = gelu_erf(v) + (float)xg.h[j];
                }
            }
#pragma unroll
        for (int off = 1; off < 32; off <<= 1)
#pragma unroll
            for (int mi = 0; mi < 2; ++mi)
#pragma unroll
                for (int e = 0; e < 16; ++e)
                    acc[mi][e] = fmaxf(acc[mi][e], __shfl_xor(acc[mi][e], off));
        if (l31 == 0) {
#pragma unroll
            for (int mi = 0; mi < 2; ++mi)
#pragma unroll
                for (int q = 0; q < 4; ++q)
#pragma unroll
                    for (int j = 0; j < 4; ++j)
                        red[w][mi * 32 + q * 8 + hi * 4 + j] = acc[mi][q * 4 + j];
        }
        __syncthreads();
        if (t < 64)
            part[((size_t)(b * 64 + y0)) * 256 + o0 + t] = fmaxf(red[0][t], red[1][t]);
    }
}

// ---------------------------------------------------------------------------
// final max over the 64 row-partials
// ---------------------------------------------------------------------------
__global__ __launch_bounds__(256) void maxfin_kernel(
    const float* __restrict__ part, float* __restrict__ out)
{
    const int o = threadIdx.x;
    const int b = blockIdx.x;
    float mx = -1e30f;
    for (int c = 0; c < 64; ++c)
        mx = fmaxf(mx, part[((size_t)(b * 64 + c)) * 256 + o]);
    out[b * 256 + o] = mx;
}

// ---------------------------------------------------------------------------
extern "C" void kernel_launch(void* const* d_in, const int* in_sizes, int n_in,
                              void* d_out, int out_size, void* d_ws, size_t ws_size,
                              hipStream_t stream)
{
    const float* in0  = (const float*)d_in[0];
    const float* in1  = (const float*)d_in[1];
    const float* w_q  = (const float*)d_in[2];
    const float* b_q  = (const float*)d_in[3];
    const float* w_k  = (const float*)d_in[4];
    const float* b_k  = (const float*)d_in[5];
    const float* w_v  = (const float*)d_in[6];
    const float* b_v  = (const float*)d_in[7];
    const float* w_o  = (const float*)d_in[8];
    const float* b_o  = (const float*)d_in[9];
    const float* bn0g = (const float*)d_in[10];
    const float* bn0b = (const float*)d_in[11];
    const float* bn0m = (const float*)d_in[12];
    const float* bn0v = (const float*)d_in[13];
    const float* cbw0 = (const float*)d_in[14];
    const float* cbb0 = (const float*)d_in[15];
    const float* cb0g = (const float*)d_in[16];
    const float* cb0b = (const float*)d_in[17];
    const float* cb0m = (const float*)d_in[18];
    const float* cb0v = (const float*)d_in[19];
    const float* cbw1 = (const float*)d_in[20];
    const float* cbb1 = (const float*)d_in[21];
    const float* cb1g = (const float*)d_in[22];
    const float* cb1b = (const float*)d_in[23];
    const float* cb1m = (const float*)d_in[24];
    const float* cb1v = (const float*)d_in[25];

    char* wsb = (char*)d_ws;
    const size_t MB = 1u << 20;
    __bf16* Xt0c = (__bf16*)(wsb);
    __bf16* Xin1c= (__bf16*)(wsb + 16 * MB);
    __bf16* Opart= (__bf16*)(wsb + 16 * MB);
    __bf16* Qswz = (__bf16*)(wsb + 24 * MB);
    __bf16* x0   = (__bf16*)(wsb + 24 * MB);
    __bf16* Kswz = (__bf16*)(wsb + 28 * MB);
    __bf16* y0   = (__bf16*)(wsb + 24 * MB);
    __bf16* Vswz = (__bf16*)(wsb + 32 * MB);
    __bf16* wqb  = (__bf16*)(wsb + 40 * MB);
    __bf16* wkb  = (__bf16*)(wsb + 40 * MB + 65536);
    __bf16* wvb  = (__bf16*)(wsb + 40 * MB + 2 * 65536);
    __bf16* wob  = (__bf16*)(wsb + 40 * MB + 3 * 65536);
    __bf16* Wt0  = (__bf16*)(wsb + 40 * MB + 4 * 65536);              // 2359296 B
    __bf16* Wt1  = (__bf16*)(wsb + 40 * MB + 4 * 65536 + 2359296);    // 1179648 B
    float*  Mpart= (float*)(wsb + 44 * MB);
    float*  Lpart= (float*)(wsb + 44 * MB + 131072);
    float*  part = (float*)(wsb + 44 * MB + 2 * 131072);
    float* outp = (float*)d_out;

    nhwc_cast2_kernel<<<dim3(64, 4, 8), 256, 0, stream>>>(in0, in1, Xt0c, Xin1c);
    wtrans_kernel<<<1280, 256, 0, stream>>>(cbw0, cbw1, w_q, w_k, w_v, w_o,
                                            Wt0, Wt1, wqb, wkb, wvb, wob);
    proj_mfma_kernel<<<dim3(32, 1, 12), 256, 0, stream>>>(
        Xt0c, Xin1c, wqb, wkb, wvb, b_q, b_k, b_v, Vswz, Kswz, Qswz);
    attn_mfma_kernel<<<1024, 256, 0, stream>>>(Qswz, Kswz, Vswz, Opart, Mpart, Lpart);
    attn_merge_kernel<<<256, 256, 0, stream>>>(Opart, Mpart, Lpart, x0);
    convo_mfma_kernel<<<dim3(32, 2, 4), 256, 0, stream>>>(
        x0, wob, b_o, bn0g, bn0b, bn0m, bn0v, Xt0c);
    conv3x3_mfma_kernel<512, false><<<1024, 128, 0, stream>>>(
        Xt0c, Wt0, cbb0, cb0g, cb0b, cb0m, cb0v, y0, nullptr, nullptr);
    conv3x3_mfma_kernel<256, true><<<1024, 128, 0, stream>>>(
        y0, Wt1, cbb1, cb1g, cb1b, cb1m, cb1v, nullptr, Xt0c, part);
    maxfin_kernel<<<4, 256, 0, stream>>>(part, outp);
}

// Round 22
// 215.018 us; speedup vs baseline: 1.0562x; 1.0562x over previous
//
#include <hip/hip_runtime.h>
#include <math.h>

#define B_ 4
#define C_ 256
#define CH_ 128
#define NN 4096   // H*W = 64*64

typedef __bf16 bf16x8 __attribute__((ext_vector_type(8)));
typedef float f32x16 __attribute__((ext_vector_type(16)));
typedef unsigned int u32;

__device__ __forceinline__ float gelu_erf(float x) {
    return 0.5f * x * (1.0f + erff(x * 0.7071067811865476f));
}

__device__ __forceinline__ u32 pkbf(float a, float b) {
    union { __bf16 h[2]; u32 u; } x;
    x.h[0] = (__bf16)a; x.h[1] = (__bf16)b;
    return x.u;
}

// ---------------------------------------------------------------------------
// NCHW fp32 -> channel-chunked bf16 [b][ch/16][4096][16], both inputs.
// ---------------------------------------------------------------------------
__global__ __launch_bounds__(256) void nhwc_cast2_kernel(
    const float* __restrict__ in0, const float* __restrict__ in1,
    __bf16* __restrict__ Xt0c, __bf16* __restrict__ Xin1c)
{
    __shared__ float Lt[64][65];
    const int t = threadIdx.x;
    const int p0 = blockIdx.x * 64;
    const int c0 = blockIdx.y * 64;
    const int z = blockIdx.z;
    const int b = z & 3;
    const float* src; __bf16* dst; int chbase, nch;
    if (z < 4) { src = in0; dst = Xt0c;  chbase = 256; nch = 32; }
    else       { src = in1; dst = Xin1c; chbase = 0;   nch = 16; }
#pragma unroll
    for (int i = 0; i < 16; ++i) {
        int idx = t + i * 256;
        int c = idx >> 6, p = idx & 63;
        Lt[c][p] = src[((size_t)(b * 256 + c0 + c)) * 4096 + p0 + p];
    }
    __syncthreads();
#pragma unroll
    for (int i = 0; i < 16; ++i) {
        int idx = t + i * 256;
        int p = idx >> 6, c = idx & 63;
        const int ch = chbase + c0 + c;
        dst[(((size_t)(b * nch + (ch >> 4)) * 4096) + p0 + p) * 16 + (ch & 15)]
            = (__bf16)Lt[c][p];
    }
}

// ---------------------------------------------------------------------------
// Weight transform.
// ---------------------------------------------------------------------------
__global__ __launch_bounds__(256) void wtrans_kernel(
    const float* __restrict__ w0, const float* __restrict__ w1,
    const float* __restrict__ wq, const float* __restrict__ wk,
    const float* __restrict__ wv, const float* __restrict__ wo,
    __bf16* __restrict__ Wt0, __bf16* __restrict__ Wt1,
    __bf16* __restrict__ wqb, __bf16* __restrict__ wkb,
    __bf16* __restrict__ wvb, __bf16* __restrict__ wob)
{
    int id = blockIdx.x * 256 + threadIdx.x;
    if (id < 131072) {
        int o = id >> 9, ci = id & 511;
        const float* s = w0 + (size_t)id * 9;
        const int chunk = ci >> 4, f = o >> 5;
        const int lane = (o & 31) + 32 * ((ci >> 3) & 1);
        const int j = ci & 7;
#pragma unroll
        for (int k = 0; k < 9; ++k)
            Wt0[((size_t)(chunk * 9 + k) * 8 + f) * 512 + lane * 8 + j] = (__bf16)s[k];
    } else if (id < 196608) {
        int id2 = id - 131072;
        int o = id2 >> 8, ci = id2 & 255;
        const float* s = w1 + (size_t)id2 * 9;
        const int chunk = ci >> 4, f = o >> 5;
        const int lane = (o & 31) + 32 * ((ci >> 3) & 1);
        const int j = ci & 7;
#pragma unroll
        for (int k = 0; k < 9; ++k)
            Wt1[((size_t)(chunk * 9 + k) * 8 + f) * 512 + lane * 8 + j] = (__bf16)s[k];
    } else {
        int id3 = id - 196608;     // 0..131071
        int sel = id3 >> 15;
        int k = id3 & 32767;
        const float* s = sel == 0 ? wq : sel == 1 ? wk : sel == 2 ? wv : wo;
        __bf16* d = sel == 0 ? wqb : sel == 1 ? wkb : sel == 2 ? wvb : wob;
        d[k] = (__bf16)s[k];
    }
}

// ---------------------------------------------------------------------------
// 1x1 projections via MFMA; inputs channel-chunked, outputs frag-major.
// ---------------------------------------------------------------------------
__global__ __launch_bounds__(256) void proj_mfma_kernel(
    const __bf16* __restrict__ Xt0c,  // [4][32][4096][16], in0 at chunks 16-31
    const __bf16* __restrict__ Xin1c, // [4][16][4096][16]
    const __bf16* __restrict__ wqb, const __bf16* __restrict__ wkb,
    const __bf16* __restrict__ wvb,
    const float* __restrict__ bq, const float* __restrict__ bk,
    const float* __restrict__ bv,
    __bf16* __restrict__ Vswz, __bf16* __restrict__ Kswz, __bf16* __restrict__ Qswz)
{
    __shared__ __align__(16) __bf16 Vt[4][64][80];
    __shared__ float biasl[128];

    const int t = threadIdx.x;
    const int which = blockIdx.z % 3;
    const int b = blockIdx.z / 3;
    const int p0 = blockIdx.x * 128;

    const __bf16* W = which == 0 ? wqb : which == 1 ? wkb : wvb;
    const float* bias = which == 0 ? bq : which == 1 ? bk : bv;
    const __bf16* src = (which == 2)
        ? Xin1c + (size_t)b * 16 * 4096 * 16
        : Xt0c  + ((size_t)(b * 32 + 16)) * 4096 * 16;

    if (t < 128) biasl[t] = bias[t];
    __syncthreads();

    const int lane = t & 63, w = t >> 6;
    const int l31 = lane & 31, hi = lane >> 5;
    const int wo2 = w >> 1, wp2 = w & 1;
    const int ob = wo2 * 64;
    const int pb = p0 + wp2 * 64;

    f32x16 acc[2][2];
#pragma unroll
    for (int i = 0; i < 2; ++i)
#pragma unroll
        for (int j = 0; j < 2; ++j)
#pragma unroll
            for (int e = 0; e < 16; ++e) acc[i][j][e] = 0.f;

#pragma unroll
    for (int kc = 0; kc < 16; ++kc) {
        bf16x8 a0 = *(const bf16x8*)&W[(size_t)(ob + l31) * 256 + hi * 8 + kc * 16];
        bf16x8 a1 = *(const bf16x8*)&W[(size_t)(ob + 32 + l31) * 256 + hi * 8 + kc * 16];
        bf16x8 b0 = *(const bf16x8*)&src[((size_t)kc * 4096 + pb + l31) * 16 + hi * 8];
        bf16x8 b1 = *(const bf16x8*)&src[((size_t)kc * 4096 + pb + 32 + l31) * 16 + hi * 8];
        acc[0][0] = __builtin_amdgcn_mfma_f32_32x32x16_bf16(a0, b0, acc[0][0], 0, 0, 0);
        acc[0][1] = __builtin_amdgcn_mfma_f32_32x32x16_bf16(a0, b1, acc[0][1], 0, 0, 0);
        acc[1][0] = __builtin_amdgcn_mfma_f32_32x32x16_bf16(a1, b0, acc[1][0], 0, 0, 0);
        acc[1][1] = __builtin_amdgcn_mfma_f32_32x32x16_bf16(a1, b1, acc[1][1], 0, 0, 0);
    }

    if (which) {
        __bf16* dst = (which == 1 ? Kswz : Qswz) + (size_t)b * NN * CH_;
#pragma unroll
        for (int mi = 0; mi < 2; ++mi)
#pragma unroll
            for (int nx = 0; nx < 2; ++nx) {
                const int tile = (pb >> 5) + nx;
#pragma unroll
                for (int q4 = 0; q4 < 4; ++q4) {
                    const int ic = (ob >> 4) + mi * 2 + (q4 >> 1);
                    const int og = ob + mi * 32 + q4 * 8 + hi * 4;
                    __bf16 pk[4];
#pragma unroll
                    for (int j = 0; j < 4; ++j)
                        pk[j] = (__bf16)(acc[mi][nx][q4 * 4 + j] + biasl[og + j]);
                    const size_t el = ((size_t)(tile * 8 + ic) * 64
                                       + l31 + 32 * (q4 & 1)) * 8 + hi * 4;
                    *(uint2*)&dst[el] = *(const uint2*)pk;
                }
            }
    } else {
#pragma unroll
        for (int mi = 0; mi < 2; ++mi)
#pragma unroll
            for (int nx = 0; nx < 2; ++nx) {
                const int ploc = nx * 32 + l31;
#pragma unroll
                for (int q4 = 0; q4 < 4; ++q4) {
                    const int oloc = mi * 32 + q4 * 8 + hi * 4;
#pragma unroll
                    for (int j = 0; j < 4; ++j)
                        Vt[w][oloc + j][ploc] =
                            (__bf16)(acc[mi][nx][q4 * 4 + j] + biasl[ob + oloc + j]);
                }
            }
        __syncthreads();
        __bf16* dst = Vswz + (size_t)b * NN * CH_;
#pragma unroll
        for (int s = 0; s < 8; ++s) {
            const int tl = s >> 2, jc = (s >> 1) & 1, il = s & 1;
            const int tile_g = (pb >> 5) + tl;
            const int icf_g = (ob >> 5) + il;
            const int i_loc = il * 32 + l31;
            const int kk = tl * 32 + jc * 16 + hi * 8;
            uint4 v = *(const uint4*)&Vt[w][i_loc][kk];
            const size_t el = ((size_t)((tile_g * 2 + jc) * 4 + icf_g) * 64 + lane) * 8;
            *(uint4*)&dst[el] = v;
        }
    }
}

// ---------------------------------------------------------------------------
// MFMA bf16 flash attention — R20-measured-best (70.7us): single-tile loop,
// split K/V bases (in-range load immediates), v_max3-fusable max tree,
// __expf softmax. (R21's exp2 variant perturbed codegen -> spill; reverted.)
// grid 1024, block 256.
// ---------------------------------------------------------------------------
__global__ __launch_bounds__(256, 4) void attn_mfma_kernel(
    const __bf16* __restrict__ Qswz, const __bf16* __restrict__ Kswz,
    const __bf16* __restrict__ Vswz,
    __bf16* __restrict__ Opart, float* __restrict__ Mpart, float* __restrict__ Lpart)
{
    __shared__ __bf16 Op[4][128][34];
    __shared__ float Ml[4][32], Ll[4][32];

    const int t = threadIdx.x;
    const int lane = t & 63;
    const int w = t >> 6;
    const int l31 = lane & 31;
    const int hi = lane >> 5;

    const int bid = blockIdx.x;
    const int xcd = bid & 7;
    const int b = xcd >> 1;
    const int local = bid >> 3;
    const int qt = (xcd & 1) * 64 + (local & 63);
    const int half = local >> 6;
    const int q0 = qt * 32;

    const __bf16* Qs = Qswz + (size_t)b * NN * CH_ + (size_t)qt * 4096 + lane * 8;
    bf16x8 qf[8];
#pragma unroll
    for (int ic = 0; ic < 8; ++ic) qf[ic] = *(const bf16x8*)(Qs + ic * 512);

    const __bf16* Ks = Kswz + (size_t)b * NN * CH_ + lane * 8;
    const __bf16* Vs = Vswz + (size_t)b * NN * CH_ + lane * 8;

    f32x16 oacc[4];
#pragma unroll
    for (int i = 0; i < 4; ++i)
#pragma unroll
        for (int e = 0; e < 16; ++e) oacc[i][e] = 0.f;

    float m = -3e38f, lsum = 0.f;
    const int tbase = half * 64 + w * 16;

    for (int jt = 0; jt < 16; ++jt) {
        const int tile = tbase + jt;
        f32x16 s;
#pragma unroll
        for (int e = 0; e < 16; ++e) s[e] = 0.f;
        // split bases: all load immediates stay within +-4096B
        const __bf16* KtA = Ks + (size_t)tile * 4096;
        const __bf16* KtB = KtA + 2048;
#pragma unroll
        for (int ic = 0; ic < 4; ++ic) {
            bf16x8 kf0 = *(const bf16x8*)(KtA + ic * 512);
            bf16x8 kf1 = *(const bf16x8*)(KtB + ic * 512);
            s = __builtin_amdgcn_mfma_f32_32x32x16_bf16(kf0, qf[ic], s, 0, 0, 0);
            s = __builtin_amdgcn_mfma_f32_32x32x16_bf16(kf1, qf[ic + 4], s, 0, 0, 0);
        }
        // max tree via v_max3-fusable triples
        float t8[8];
#pragma unroll
        for (int e = 0; e < 8; ++e) t8[e] = fmaxf(s[e], s[e + 8]);
        const float ta = fmaxf(fmaxf(t8[0], t8[1]), t8[2]);
        const float tb = fmaxf(fmaxf(t8[3], t8[4]), t8[5]);
        const float tc = fmaxf(t8[6], t8[7]);
        float mu = fmaxf(fmaxf(ta, tb), tc);
        const float pm = fmaxf(mu, __shfl_xor(mu, 32));
        if (!__all(pm <= m + 8.f)) {
            const float mn = fmaxf(m, pm);
            const float al = __expf(m - mn);
            m = mn;
            lsum *= al;
#pragma unroll
            for (int i = 0; i < 4; ++i)
#pragma unroll
                for (int e = 0; e < 16; ++e) oacc[i][e] *= al;
        }
#pragma unroll
        for (int e = 0; e < 16; ++e) s[e] = __expf(s[e] - m);
        float s8[8];
#pragma unroll
        for (int e = 0; e < 8; ++e) s8[e] = s[e] + s[e + 8];
#pragma unroll
        for (int e = 0; e < 4; ++e) s8[e] += s8[e + 4];
        s8[0] += s8[2]; s8[1] += s8[3];
        float su = s8[0] + s8[1];
        lsum += su + __shfl_xor(su, 32);

        const __bf16* VtA = Vs + (size_t)tile * 4096;
        const __bf16* VtB = VtA + 2048;
        {
            u32 w0 = pkbf(s[0], s[1]), w1 = pkbf(s[2], s[3]);
            u32 w2 = pkbf(s[4], s[5]), w3 = pkbf(s[6], s[7]);
            asm("v_permlane32_swap_b32 %0, %1" : "+v"(w0), "+v"(w2));
            asm("v_permlane32_swap_b32 %0, %1" : "+v"(w1), "+v"(w3));
            union { u32 u4[4]; bf16x8 v; } pB;
            pB.u4[0] = w0; pB.u4[1] = w1; pB.u4[2] = w2; pB.u4[3] = w3;
#pragma unroll
            for (int icf = 0; icf < 4; ++icf) {
                bf16x8 vf = *(const bf16x8*)(VtA + icf * 512);
                oacc[icf] = __builtin_amdgcn_mfma_f32_32x32x16_bf16(vf, pB.v, oacc[icf], 0, 0, 0);
            }
        }
        {
            u32 w0 = pkbf(s[8], s[9]), w1 = pkbf(s[10], s[11]);
            u32 w2 = pkbf(s[12], s[13]), w3 = pkbf(s[14], s[15]);
            asm("v_permlane32_swap_b32 %0, %1" : "+v"(w0), "+v"(w2));
            asm("v_permlane32_swap_b32 %0, %1" : "+v"(w1), "+v"(w3));
            union { u32 u4[4]; bf16x8 v; } pB;
            pB.u4[0] = w0; pB.u4[1] = w1; pB.u4[2] = w2; pB.u4[3] = w3;
#pragma unroll
            for (int icf = 0; icf < 4; ++icf) {
                bf16x8 vf = *(const bf16x8*)(VtB + icf * 512);
                oacc[icf] = __builtin_amdgcn_mfma_f32_32x32x16_bf16(vf, pB.v, oacc[icf], 0, 0, 0);
            }
        }
    }

#pragma unroll
    for (int icf = 0; icf < 4; ++icf)
#pragma unroll
        for (int q = 0; q < 16; ++q) {
            const int row = icf * 32 + (q & 3) + 8 * (q >> 2) + 4 * hi;
            Op[w][row][l31] = (__bf16)oacc[icf][q];
        }
    if (hi == 0) { Ml[w][l31] = m; Ll[w][l31] = lsum; }
    __syncthreads();
    {
        const int q = t & 31;
        const int i0g = (t >> 5) * 16;
        const float m0 = Ml[0][q], m1 = Ml[1][q], m2 = Ml[2][q], m3 = Ml[3][q];
        const float ms = fmaxf(fmaxf(m0, m1), fmaxf(m2, m3));
        const float a0 = __expf(m0 - ms), a1 = __expf(m1 - ms);
        const float a2 = __expf(m2 - ms), a3 = __expf(m3 - ms);
        const float den = a0 * Ll[0][q] + a1 * Ll[1][q] + a2 * Ll[2][q] + a3 * Ll[3][q];
        union { __bf16 h[16]; uint4 u4[2]; } pk;
#pragma unroll
        for (int ii = 0; ii < 16; ++ii) {
            const int i = i0g + ii;
            pk.h[ii] = (__bf16)(a0 * (float)Op[0][i][q] + a1 * (float)Op[1][i][q]
                              + a2 * (float)Op[2][i][q] + a3 * (float)Op[3][i][q]);
        }
        const size_t base = ((size_t)((half * 4 + b) * NN) + q0 + q) * CH_ + i0g;
        *(uint4*)&Opart[base] = pk.u4[0];
        *(uint4*)&Opart[base + 8] = pk.u4[1];
        if (t < 32) {
            Mpart[(size_t)(half * 4 + b) * NN + q0 + q] = ms;
            Lpart[(size_t)(half * 4 + b) * NN + q0 + q] = den;
        }
    }
}

// ---------------------------------------------------------------------------
// Merge the 2 KV-half partials -> x0 bf16 pos-major [4][4096][128]
// ---------------------------------------------------------------------------
__global__ __launch_bounds__(256) void attn_merge_kernel(
    const __bf16* __restrict__ Opart, const float* __restrict__ Mpart,
    const float* __restrict__ Lpart, __bf16* __restrict__ x0)
{
    const int id = blockIdx.x * 256 + threadIdx.x;
    const int qg = id >> 2;
    const int i0 = (id & 3) * 32;
    const int b = qg >> 12, q = qg & 4095;
    const size_t idx0 = (size_t)b * NN + q;
    const size_t idx1 = (size_t)(4 + b) * NN + q;
    const float m0 = Mpart[idx0], m1 = Mpart[idx1];
    const float ms = fmaxf(m0, m1);
    const float a0 = __expf(m0 - ms), a1 = __expf(m1 - ms);
    const float inv = 1.f / (a0 * Lpart[idx0] + a1 * Lpart[idx1]);
    const __bf16* O0 = &Opart[idx0 * CH_ + i0];
    const __bf16* O1 = &Opart[idx1 * CH_ + i0];
    union { __bf16 h[32]; uint4 u4[4]; } ov;
#pragma unroll
    for (int ii = 0; ii < 32; ++ii)
        ov.h[ii] = (__bf16)((a0 * (float)O0[ii] + a1 * (float)O1[ii]) * inv);
    uint4* dst = (uint4*)&x0[((size_t)b * NN + q) * CH_ + i0];
#pragma unroll
    for (int s = 0; s < 4; ++s) dst[s] = ov.u4[s];
}

// ---------------------------------------------------------------------------
// conv_o (1x1, 128->256) via MFMA + BN + GELU -> Xt0c chunks 0-15
// ---------------------------------------------------------------------------
__global__ __launch_bounds__(256) void convo_mfma_kernel(
    const __bf16* __restrict__ x0, const __bf16* __restrict__ wob,
    const float* __restrict__ bo,
    const float* __restrict__ g, const float* __restrict__ bb,
    const float* __restrict__ mm, const float* __restrict__ vv,
    __bf16* __restrict__ Xt0c)
{
    __shared__ float scb[128], shb[128], bsb[128];
    const int t = threadIdx.x;
    const int p0 = blockIdx.x * 128;
    const int o0 = blockIdx.y * 128;
    const int b = blockIdx.z;
    if (t < 128) {
        const int o = o0 + t;
        const float sc = g[o] * rsqrtf(vv[o] + 1e-5f);
        scb[t] = sc; shb[t] = bb[o] - mm[o] * sc; bsb[t] = bo[o];
    }
    __syncthreads();

    const int lane = t & 63, w = t >> 6;
    const int l31 = lane & 31, hi = lane >> 5;
    const int wo2 = w >> 1, wp2 = w & 1;
    const int ob = o0 + wo2 * 64;
    const int pb = p0 + wp2 * 64;

    f32x16 acc[2][2];
#pragma unroll
    for (int i = 0; i < 2; ++i)
#pragma unroll
        for (int j = 0; j < 2; ++j)
#pragma unroll
            for (int e = 0; e < 16; ++e) acc[i][j][e] = 0.f;

#pragma unroll
    for (int kc = 0; kc < 8; ++kc) {
        bf16x8 a0 = *(const bf16x8*)&wob[(size_t)(ob + l31) * 128 + hi * 8 + kc * 16];
        bf16x8 a1 = *(const bf16x8*)&wob[(size_t)(ob + 32 + l31) * 128 + hi * 8 + kc * 16];
        bf16x8 b0 = *(const bf16x8*)&x0[((size_t)(b * NN) + pb + l31) * 128 + hi * 8 + kc * 16];
        bf16x8 b1 = *(const bf16x8*)&x0[((size_t)(b * NN) + pb + 32 + l31) * 128 + hi * 8 + kc * 16];
        acc[0][0] = __builtin_amdgcn_mfma_f32_32x32x16_bf16(a0, b0, acc[0][0], 0, 0, 0);
        acc[0][1] = __builtin_amdgcn_mfma_f32_32x32x16_bf16(a0, b1, acc[0][1], 0, 0, 0);
        acc[1][0] = __builtin_amdgcn_mfma_f32_32x32x16_bf16(a1, b0, acc[1][0], 0, 0, 0);
        acc[1][1] = __builtin_amdgcn_mfma_f32_32x32x16_bf16(a1, b1, acc[1][1], 0, 0, 0);
    }

#pragma unroll
    for (int mi = 0; mi < 2; ++mi)
#pragma unroll
        for (int nx = 0; nx < 2; ++nx) {
            const int p = pb + nx * 32 + l31;
#pragma unroll
            for (int q4 = 0; q4 < 4; ++q4) {
                const int ol = wo2 * 64 + mi * 32 + q4 * 8 + hi * 4;
                const int chg = o0 + ol;   // global out channel
                __bf16 pk[4];
#pragma unroll
                for (int j = 0; j < 4; ++j) {
                    float v = acc[mi][nx][q4 * 4 + j] + bsb[ol + j];
                    v = v * scb[ol + j] + shb[ol + j];
                    pk[j] = (__bf16)gelu_erf(v);
                }
                *(uint2*)&Xt0c[(((size_t)(b * 32 + (chg >> 4)) * 4096) + p) * 16 + (chg & 15)]
                    = *(const uint2*)pk;
            }
        }
}

// ---------------------------------------------------------------------------
// 3x3 conv via MFMA — channel-chunked input, raw barrier, reg weights,
// L2-aware XCD map. (R17-proven, unchanged.)
// ---------------------------------------------------------------------------
template<int IC, bool FUSEMAX>
__global__ __launch_bounds__(128) void conv3x3_mfma_kernel(
    const __bf16* __restrict__ Xsrc,   // chunked [4][IC/16][4096][16]
    const __bf16* __restrict__ Wf,     // frag-major [chunk16][9][8][64][8]
    const float* __restrict__ bias, const float* __restrict__ bng,
    const float* __restrict__ bnb, const float* __restrict__ bnm,
    const float* __restrict__ bnv,
    __bf16* __restrict__ out,          // chunked [4][16][4096][16] (FUSEMAX=0)
    const __bf16* __restrict__ Xg,     // Xt0c (x0g at chunks 0-15) (FUSEMAX=1)
    float* __restrict__ part)          // [4][64][256] partial max (FUSEMAX=1)
{
    constexpr int NC = IC / 16;
    __shared__ __align__(16) char Tl[2][6336];   // [3 rows][66 xh][16 ci] bf16
    __shared__ float scb[64], shb[64], bsb[64];
    __shared__ float red[2][64];

    const int t = threadIdx.x;
    const int bid = blockIdx.x;
    const int xcd = bid & 7, local = bid >> 3;        // local 0..127
    const int b = xcd >> 1, yhi = xcd & 1;
    const int y0 = yhi * 32 + (local & 31);           // output row
    const int m = local >> 5;
    const int o0 = m * 64;

    if (t < 64) {
        const int o = o0 + t;
        const float sc = bng[o] * rsqrtf(bnv[o] + 1e-5f);
        scb[t] = sc; shb[t] = bnb[o] - bnm[o] * sc; bsb[t] = bias[o];
    }

    const int lane = t & 63, w = t >> 6;   // w = x-half (0,1)
    const int l31 = lane & 31, hi = lane >> 5;

    uint4 ireg[3];

    auto loadI = [&](int cc) {             // cc = input channel-chunk index
        const __bf16* base = Xsrc + ((size_t)(b * NC + cc)) * 4096 * 16;
#pragma unroll
        for (int s = 0; s < 3; ++s) {
            int u = t + s * 128;
            int g = u & 1, x = (u >> 1) & 63, r = u >> 7;   // r 0..2
            int yy = y0 - 1 + r;
            if (yy >= 0 && yy < 64)
                ireg[s] = *(const uint4*)&base[((size_t)(yy * 64 + x)) * 16 + g * 8];
            else
                ireg[s] = make_uint4(0u, 0u, 0u, 0u);
        }
    };
    auto writeI = [&](char* dst) {
#pragma unroll
        for (int s = 0; s < 3; ++s) {
            int u = t + s * 128;
            int g = u & 1, x = (u >> 1) & 63, r = u >> 7;
            int xh = x + 1;
            int byte = r * 2112 + ((xh * 32 + g * 16) ^ ((xh & 7) << 4));
            *(uint4*)(dst + byte) = ireg[s];
        }
        if (t < 12) {
            int g = t & 1, side = (t >> 1) & 1, r = t >> 2;
            int xh = side ? 65 : 0;
            int byte = r * 2112 + ((xh * 32 + g * 16) ^ ((xh & 7) << 4));
            *(uint4*)(dst + byte) = make_uint4(0u, 0u, 0u, 0u);
        }
    };

    const __bf16* Wb = Wf + ((size_t)(m * 2) * 64 + lane) * 8;
    bf16x8 wA[9][2];
    auto loadA = [&](int c) {
#pragma unroll
        for (int k9 = 0; k9 < 9; ++k9) {
            const __bf16* wp = Wb + (size_t)(c * 9 + k9) * 4096;
            wA[k9][0] = *(const bf16x8*)(wp);
            wA[k9][1] = *(const bf16x8*)(wp + 512);
        }
    };

    f32x16 acc[2];
#pragma unroll
    for (int i = 0; i < 2; ++i)
#pragma unroll
        for (int e = 0; e < 16; ++e) acc[i][e] = 0.f;

    int Boff[3];
#pragma unroll
    for (int dx = 0; dx < 3; ++dx) {
        int xh = w * 32 + l31 + dx;
        Boff[dx] = (xh * 32 + hi * 16) ^ ((xh & 7) << 4);
    }

    auto compute = [&](const char* Tb) {
#pragma unroll
        for (int k9 = 0; k9 < 9; ++k9) {
            const int dy = k9 / 3, dx = k9 % 3;
            bf16x8 bv = *(const bf16x8*)(Tb + dy * 2112 + Boff[dx]);
            acc[0] = __builtin_amdgcn_mfma_f32_32x32x16_bf16(wA[k9][0], bv, acc[0], 0, 0, 0);
            acc[1] = __builtin_amdgcn_mfma_f32_32x32x16_bf16(wA[k9][1], bv, acc[1], 0, 0, 0);
        }
    };

    loadI(0); loadA(0);
    writeI(Tl[0]);
    asm volatile("s_waitcnt lgkmcnt(0)" ::: "memory");
    __builtin_amdgcn_s_barrier();
    for (int c = 0; c < NC; ++c) {
        const int cur = c & 1;
        if (c + 1 < NC) loadI(c + 1);
        compute(Tl[cur]);
        if (c + 1 < NC) { loadA(c + 1); writeI(Tl[cur ^ 1]); }
        asm volatile("s_waitcnt lgkmcnt(0)" ::: "memory");
        __builtin_amdgcn_s_barrier();
    }

    const int p = y0 * 64 + w * 32 + l31;
    if constexpr (!FUSEMAX) {
#pragma unroll
        for (int mi = 0; mi < 2; ++mi)
#pragma unroll
            for (int q = 0; q < 4; ++q) {
                const int obase = mi * 32 + q * 8 + hi * 4;
                const int chg = o0 + obase;
                __bf16 pk[4];
#pragma unroll
                for (int j = 0; j < 4; ++j) {
                    float v = acc[mi][q * 4 + j] + bsb[obase + j];
                    v = v * scb[obase + j] + shb[obase + j];
                    pk[j] = (__bf16)gelu_erf(v);
                }
                *(uint2*)&out[(((size_t)(b * 16 + (chg >> 4)) * 4096) + p) * 16 + (chg & 15)]
                    = *(const uint2*)pk;
            }
    } else {
#pragma unroll
        for (int mi = 0; mi < 2; ++mi)
#pragma unroll
            for (int q = 0; q < 4; ++q) {
                const int obase = mi * 32 + q * 8 + hi * 4;
                const int chg = o0 + obase;
                union { uint2 u; __bf16 h[4]; } xg;
                xg.u = *(const uint2*)&Xg[(((size_t)(b * 32 + (chg >> 4)) * 4096) + p) * 16
                                          + (chg & 15)];
#pragma unroll
                for (int j = 0; j < 4; ++j) {
                    float v = acc[mi][q * 4 + j] + bsb[obase + j];
                    v = v * scb[obase + j] + shb[obase + j];
                    acc[mi][q * 4 + j] = gelu_erf(v) + (float)xg.h[j];
                }
            }
#pragma unroll
        for (int off = 1; off < 32; off <<= 1)
#pragma unroll
            for (int mi = 0; mi < 2; ++mi)
#pragma unroll
                for (int e = 0; e < 16; ++e)
                    acc[mi][e] = fmaxf(acc[mi][e], __shfl_xor(acc[mi][e], off));
        if (l31 == 0) {
#pragma unroll
            for (int mi = 0; mi < 2; ++mi)
#pragma unroll
                for (int q = 0; q < 4; ++q)
#pragma unroll
                    for (int j = 0; j < 4; ++j)
                        red[w][mi * 32 + q * 8 + hi * 4 + j] = acc[mi][q * 4 + j];
        }
        __syncthreads();
        if (t < 64)
            part[((size_t)(b * 64 + y0)) * 256 + o0 + t] = fmaxf(red[0][t], red[1][t]);
    }
}

// ---------------------------------------------------------------------------
// final max over the 64 row-partials
// ---------------------------------------------------------------------------
__global__ __launch_bounds__(256) void maxfin_kernel(
    const float* __restrict__ part, float* __restrict__ out)
{
    const int o = threadIdx.x;
    const int b = blockIdx.x;
    float mx = -1e30f;
    for (int c = 0; c < 64; ++c)
        mx = fmaxf(mx, part[((size_t)(b * 64 + c)) * 256 + o]);
    out[b * 256 + o] = mx;
}

// ---------------------------------------------------------------------------
extern "C" void kernel_launch(void* const* d_in, const int* in_sizes, int n_in,
                              void* d_out, int out_size, void* d_ws, size_t ws_size,
                              hipStream_t stream)
{
    const float* in0  = (const float*)d_in[0];
    const float* in1  = (const float*)d_in[1];
    const float* w_q  = (const float*)d_in[2];
    const float* b_q  = (const float*)d_in[3];
    const float* w_k  = (const float*)d_in[4];
    const float* b_k  = (const float*)d_in[5];
    const float* w_v  = (const float*)d_in[6];
    const float* b_v  = (const float*)d_in[7];
    const float* w_o  = (const float*)d_in[8];
    const float* b_o  = (const float*)d_in[9];
    const float* bn0g = (const float*)d_in[10];
    const float* bn0b = (const float*)d_in[11];
    const float* bn0m = (const float*)d_in[12];
    const float* bn0v = (const float*)d_in[13];
    const float* cbw0 = (const float*)d_in[14];
    const float* cbb0 = (const float*)d_in[15];
    const float* cb0g = (const float*)d_in[16];
    const float* cb0b = (const float*)d_in[17];
    const float* cb0m = (const float*)d_in[18];
    const float* cb0v = (const float*)d_in[19];
    const float* cbw1 = (const float*)d_in[20];
    const float* cbb1 = (const float*)d_in[21];
    const float* cb1g = (const float*)d_in[22];
    const float* cb1b = (const float*)d_in[23];
    const float* cb1m = (const float*)d_in[24];
    const float* cb1v = (const float*)d_in[25];

    char* wsb = (char*)d_ws;
    const size_t MB = 1u << 20;
    __bf16* Xt0c = (__bf16*)(wsb);
    __bf16* Xin1c= (__bf16*)(wsb + 16 * MB);
    __bf16* Opart= (__bf16*)(wsb + 16 * MB);
    __bf16* Qswz = (__bf16*)(wsb + 24 * MB);
    __bf16* x0   = (__bf16*)(wsb + 24 * MB);
    __bf16* Kswz = (__bf16*)(wsb + 28 * MB);
    __bf16* y0   = (__bf16*)(wsb + 24 * MB);
    __bf16* Vswz = (__bf16*)(wsb + 32 * MB);
    __bf16* wqb  = (__bf16*)(wsb + 40 * MB);
    __bf16* wkb  = (__bf16*)(wsb + 40 * MB + 65536);
    __bf16* wvb  = (__bf16*)(wsb + 40 * MB + 2 * 65536);
    __bf16* wob  = (__bf16*)(wsb + 40 * MB + 3 * 65536);
    __bf16* Wt0  = (__bf16*)(wsb + 40 * MB + 4 * 65536);              // 2359296 B
    __bf16* Wt1  = (__bf16*)(wsb + 40 * MB + 4 * 65536 + 2359296);    // 1179648 B
    float*  Mpart= (float*)(wsb + 44 * MB);
    float*  Lpart= (float*)(wsb + 44 * MB + 131072);
    float*  part = (float*)(wsb + 44 * MB + 2 * 131072);
    float* outp = (float*)d_out;

    nhwc_cast2_kernel<<<dim3(64, 4, 8), 256, 0, stream>>>(in0, in1, Xt0c, Xin1c);
    wtrans_kernel<<<1280, 256, 0, stream>>>(cbw0, cbw1, w_q, w_k, w_v, w_o,
                                            Wt0, Wt1, wqb, wkb, wvb, wob);
    proj_mfma_kernel<<<dim3(32, 1, 12), 256, 0, stream>>>(
        Xt0c, Xin1c, wqb, wkb, wvb, b_q, b_k, b_v, Vswz, Kswz, Qswz);
    attn_mfma_kernel<<<1024, 256, 0, stream>>>(Qswz, Kswz, Vswz, Opart, Mpart, Lpart);
    attn_merge_kernel<<<256, 256, 0, stream>>>(Opart, Mpart, Lpart, x0);
    convo_mfma_kernel<<<dim3(32, 2, 4), 256, 0, stream>>>(
        x0, wob, b_o, bn0g, bn0b, bn0m, bn0v, Xt0c);
    conv3x3_mfma_kernel<512, false><<<1024, 128, 0, stream>>>(
        Xt0c, Wt0, cbb0, cb0g, cb0b, cb0m, cb0v, y0, nullptr, nullptr);
    conv3x3_mfma_kernel<256, true><<<1024, 128, 0, stream>>>(
        y0, Wt1, cbb1, cb1g, cb1b, cb1m, cb1v, nullptr, Xt0c, part);
    maxfin_kernel<<<4, 256, 0, stream>>>(part, outp);
}